// Round 21
// baseline (45.501 us; speedup 1.0000x reference)
//
#include <hip/hip_runtime.h>
#include <hip/hip_bf16.h>
#include <math.h>

#define EMBED  768
#define SEQ    4096
#define ADIM   64
#define NBATCH 4
#define QSCALE (0.125f * 1.44269504088896340736f)

typedef __bf16 bf16;
typedef unsigned int u32;
typedef __attribute__((ext_vector_type(2))) unsigned u32x2;
typedef __attribute__((ext_vector_type(8))) __bf16 bf16x8;
typedef __attribute__((ext_vector_type(4))) __bf16 bf16x4;
typedef __attribute__((ext_vector_type(4))) float f32x4;
typedef __attribute__((ext_vector_type(16))) float f32x16;

__device__ __forceinline__ f32x4 mfma16(bf16x8 a, bf16x8 b, f32x4 c) {
  return __builtin_amdgcn_mfma_f32_16x16x32_bf16(a, b, c, 0, 0, 0);
}
__device__ __forceinline__ f32x16 mfma32(bf16x8 a, bf16x8 b, f32x16 c) {
  return __builtin_amdgcn_mfma_f32_32x32x16_bf16(a, b, c, 0, 0, 0);
}
__device__ __forceinline__ unsigned cvtpk(float lo, float hi) {
  unsigned d;
  asm("v_cvt_pk_bf16_f32 %0, %1, %2" : "=v"(d) : "v"(lo), "v"(hi));
  return d;
}
// raw native exp2 (v_exp_f32): avoids OCML denormal-fixup bloat.
__device__ __forceinline__ float exp2raw(float x) {
  float r;
  asm("v_exp_f32 %0, %1" : "=v"(r) : "v"(x));
  return r;
}
// half-wave swap: ret.x = {a_lo | b_lo}, ret.y = {a_hi | b_hi}
__device__ __forceinline__ u32x2 pl32swap(unsigned a, unsigned b) {
  return __builtin_amdgcn_permlane32_swap(a, b, false, false);
}
// async 16B-per-lane global -> LDS DMA (lane i lands at ldsbase + i*16B)
__device__ __forceinline__ void gl_lds16(const bf16* g, bf16* l) {
  __builtin_amdgcn_global_load_lds(
      (const __attribute__((address_space(1))) u32*)g,
      (__attribute__((address_space(3))) u32*)l, 16, 0, 0);
}

// ---------------------------------------------------------------------------
// Projection GEMM, M=64 rows/block at 256 THREADS (the only stable thread
// count — 512-thread variants hit the 32-VGPR starvation cliff). 256 blocks
// -> W L2 traffic HALVED vs R15 (295->147 MB; proj is ~L2-BW-bound on W).
// 4 waves, each 16 rows x all 192 cols: acc[12], 12 MFMA/step. W staging
// pattern identical to R15 (proven stride-40 bank math); X staging 2 float4
// per thread, depth-2 pipeline. __launch_bounds__(256,3): VGPR cap ~170.
// V written KV-TILE-BLOCKED Vt[b][s/32][d][s%32] (4KB/tile).
// ---------------------------------------------------------------------------
__global__ __launch_bounds__(256, 3) void proj_kernel(
    const float* __restrict__ x,
    const float* __restrict__ Wq, const float* __restrict__ Wk,
    const float* __restrict__ Wv,
    bf16* __restrict__ Qs, bf16* __restrict__ Ks, bf16* __restrict__ Vt)
{
  __shared__ bf16 Wl[2][192][40];   // 30720 B
  __shared__ bf16 Xl[2][64][40];    // 10240 B

  const int t    = threadIdx.x;
  const int lane = t & 63;
  const int w    = t >> 6;       // 0..3: rows [16w, 16w+16)
  const int r    = lane & 15;
  const int g    = lane >> 4;
  const long long row0 = (long long)blockIdx.x * 64;

  f32x4 acc[12];
  #pragma unroll
  for (int i = 0; i < 12; ++i) acc[i] = f32x4{0.f, 0.f, 0.f, 0.f};

  // W staging (R15 pattern): thread -> row t>>2 of each W, 8 cols at (t&3)*8
  const int wrow = t >> 2;              // 0..63
  const int wg   = t & 3;
  const long long woff = (long long)wrow * EMBED + wg * 8;
  const float* wqs = Wq + woff;
  const float* wks = Wk + woff;
  const float* wvs = Wv + woff;
  // X staging: thread -> row t>>2 (0..63), 8 cols at (t&3)*8
  const int xrow = t >> 2;
  const int xcol = (t & 3) * 8;
  const float* xsrc = x + (row0 + xrow) * EMBED + xcol;

  #define WWRITE(buf, base, va, vb, sc)                                      \
    {                                                                        \
      uint2 p0, p1;                                                          \
      p0.x = cvtpk(va.x * sc, va.y * sc);                                    \
      p0.y = cvtpk(va.z * sc, va.w * sc);                                    \
      p1.x = cvtpk(vb.x * sc, vb.y * sc);                                    \
      p1.y = cvtpk(vb.z * sc, vb.w * sc);                                    \
      *reinterpret_cast<uint2*>(&Wl[buf][(base) + wrow][wg * 8])     = p0;   \
      *reinterpret_cast<uint2*>(&Wl[buf][(base) + wrow][wg * 8 + 4]) = p1;   \
    }
  #define XWRITE(buf, xa, xb)                                                \
    {                                                                        \
      uint2 p0, p1;                                                          \
      p0.x = cvtpk(xa.x, xa.y); p0.y = cvtpk(xa.z, xa.w);                    \
      p1.x = cvtpk(xb.x, xb.y); p1.y = cvtpk(xb.z, xb.w);                    \
      *reinterpret_cast<uint2*>(&Xl[buf][xrow][xcol])     = p0;              \
      *reinterpret_cast<uint2*>(&Xl[buf][xrow][xcol + 4]) = p1;              \
    }

  // prologue: stage kt=0 into buf 0
  {
    float4 qa = *reinterpret_cast<const float4*>(wqs);
    float4 qb = *reinterpret_cast<const float4*>(wqs + 4);
    float4 ka = *reinterpret_cast<const float4*>(wks);
    float4 kb = *reinterpret_cast<const float4*>(wks + 4);
    float4 va = *reinterpret_cast<const float4*>(wvs);
    float4 vb = *reinterpret_cast<const float4*>(wvs + 4);
    float4 xa = *reinterpret_cast<const float4*>(xsrc);
    float4 xb = *reinterpret_cast<const float4*>(xsrc + 4);
    WWRITE(0, 0,   qa, qb, QSCALE);
    WWRITE(0, 64,  ka, kb, 1.0f);
    WWRITE(0, 128, va, vb, 1.0f);
    XWRITE(0, xa, xb);
  }
  // X depth-2: preload kt=1's X
  float4 xa_n = *reinterpret_cast<const float4*>(xsrc + 32);
  float4 xb_n = *reinterpret_cast<const float4*>(xsrc + 36);
  __syncthreads();

  int cur = 0;
  for (int kt = 0; kt < 24; ++kt) {
    // issue next-step global loads FIRST (latency hides under MFMAs)
    float4 qa, qb, ka, kb, va, vb, xa_n2, xb_n2;
    const bool pfW = kt < 23;
    if (pfW) {
      const int k0n = (kt + 1) * 32;
      qa = *reinterpret_cast<const float4*>(wqs + k0n);
      qb = *reinterpret_cast<const float4*>(wqs + k0n + 4);
      ka = *reinterpret_cast<const float4*>(wks + k0n);
      kb = *reinterpret_cast<const float4*>(wks + k0n + 4);
      va = *reinterpret_cast<const float4*>(wvs + k0n);
      vb = *reinterpret_cast<const float4*>(wvs + k0n + 4);
    }
    if (kt < 22) {
      xa_n2 = *reinterpret_cast<const float4*>(xsrc + (kt + 2) * 32);
      xb_n2 = *reinterpret_cast<const float4*>(xsrc + (kt + 2) * 32 + 4);
    }

    // compute on cur: wave w does rows [16w,16w+16) x 192 cols
    bf16x8 af = *reinterpret_cast<const bf16x8*>(&Xl[cur][w * 16 + r][g * 8]);
    #pragma unroll
    for (int i = 0; i < 12; ++i) {
      bf16x8 bfrag = *reinterpret_cast<const bf16x8*>(&Wl[cur][i * 16 + r][g * 8]);
      acc[i] = mfma16(af, bfrag, acc[i]);
    }

    // land next tile (write side of T14 split; cvt here)
    if (pfW) {
      WWRITE(cur ^ 1, 0,   qa, qb, QSCALE);
      WWRITE(cur ^ 1, 64,  ka, kb, 1.0f);
      WWRITE(cur ^ 1, 128, va, vb, 1.0f);
      XWRITE(cur ^ 1, xa_n, xb_n);
    }
    xa_n = xa_n2; xb_n = xb_n2;
    __syncthreads();
    cur ^= 1;
  }
  #undef WWRITE
  #undef XWRITE

  // epilogue: 16x16 D layout row=(g*4+j), col=r. Tiles 0-3 Q, 4-7 K, 8-11 V.
  const long long rowbase = row0 + w * 16 + g * 4;
  const int bb = (int)(rowbase >> 12);
  const int ss = (int)(rowbase & 4095);
  #pragma unroll
  for (int i = 0; i < 12; ++i) {
    if (i < 4) {
      #pragma unroll
      for (int j = 0; j < 4; ++j)
        Qs[(rowbase + j) * ADIM + i * 16 + r] = (bf16)(acc[i][j]);
    } else if (i < 8) {
      #pragma unroll
      for (int j = 0; j < 4; ++j)
        Ks[(rowbase + j) * ADIM + (i - 4) * 16 + r] = (bf16)(acc[i][j]);
    } else {
      const int d = (i - 8) * 16 + r;
      bf16x4 pack;
      pack[0] = (bf16)(acc[i][0]); pack[1] = (bf16)(acc[i][1]);
      pack[2] = (bf16)(acc[i][2]); pack[3] = (bf16)(acc[i][3]);
      *reinterpret_cast<bf16x4*>(
          &Vt[(((long long)bb * 128 + (ss >> 5)) * 64 + d) * 32 + (ss & 31)]) = pack;
    }
  }
}

// ---------------------------------------------------------------------------
// Flash attention — R20 VERBATIM (42.8us config): K+V exact-line LDS-DMA,
// prefetch-distance-1, max-free softmax with raw v_exp_f32, permlane32_swap
// P^T build, tile-1 prologue prefetch + raw s_barrier combine.
// ---------------------------------------------------------------------------
__global__ __launch_bounds__(768) void attn_kernel(
    const bf16* __restrict__ Qs, const bf16* __restrict__ Ks,
    const bf16* __restrict__ Vt, float* __restrict__ out)
{
  __shared__ bf16 Kst[12][2048];                // 48 KB
  __shared__ bf16 Vst[12][2048];                // 48 KB
  __shared__ unsigned short OldsU[12][32][72];  // 55.3 KB
  __shared__ float Llds[12][32];                // 1.5 KB

  const int t    = threadIdx.x;
  const int lane = t & 63;
  const int w    = t >> 6;        // 0..11
  const int q    = lane & 31;
  const int h    = lane >> 5;
  const int bi   = blockIdx.x;    // 256 blocks
  const int b    = bi & 3;
  const int p    = bi >> 2;       // 0..63

  const bf16* Qb = Qs + (long long)b * SEQ * ADIM;
  const bf16* Kb = Ks + (long long)b * SEQ * ADIM;
  const bf16* Vb = Vt + (long long)b * SEQ * ADIM;  // [128][64][32] tiled

  const int Ri = lane >> 3;
  const int ci = lane & 7;
  const bf16* kdma = Kb + (long long)Ri * ADIM + (ci ^ Ri) * 8;
  bf16* kslot = &Kst[w][0];
  const int vd = lane >> 2;
  const int vc = lane & 3;
  const bf16* vdma = Vb + (long long)vd * 32 + ((vc ^ (vd & 3)) * 8);
  bf16* vslot = &Vst[w][0];

  const char* kbase = (const char*)kslot;
  const bf16x8* kfp0 = (const bf16x8*)(kbase + q * 128 + (((0 + h) ^ (q & 7)) << 4));
  const bf16x8* kfp1 = (const bf16x8*)(kbase + q * 128 + (((2 + h) ^ (q & 7)) << 4));
  const bf16x8* kfp2 = (const bf16x8*)(kbase + q * 128 + (((4 + h) ^ (q & 7)) << 4));
  const bf16x8* kfp3 = (const bf16x8*)(kbase + q * 128 + (((6 + h) ^ (q & 7)) << 4));
  const char* vbase = (const char*)vslot;
  const bf16x8* vfp00 = (const bf16x8*)(vbase + q * 64        + (((0 + h) ^ (q & 3)) << 4));
  const bf16x8* vfp01 = (const bf16x8*)(vbase + q * 64        + (((2 + h) ^ (q & 3)) << 4));
  const bf16x8* vfp10 = (const bf16x8*)(vbase + 2048 + q * 64 + (((0 + h) ^ (q & 3)) << 4));
  const bf16x8* vfp11 = (const bf16x8*)(vbase + 2048 + q * 64 + (((2 + h) ^ (q & 3)) << 4));

  #define KVDMA(st_)                                                         \
    {                                                                        \
      const bf16* ksrc = kdma + (long long)((st_) * 32) * ADIM;              \
      gl_lds16(ksrc,             kslot);                                     \
      gl_lds16(ksrc +  8 * ADIM, kslot + 512);                               \
      gl_lds16(ksrc + 16 * ADIM, kslot + 1024);                              \
      gl_lds16(ksrc + 24 * ADIM, kslot + 1536);                              \
      const bf16* vsrc = vdma + (long long)(st_) * 2048;                     \
      gl_lds16(vsrc,        vslot);                                          \
      gl_lds16(vsrc +  512, vslot + 512);                                    \
      gl_lds16(vsrc + 1024, vslot + 1024);                                   \
      gl_lds16(vsrc + 1536, vslot + 1536);                                   \
    }

  // prologue DMA for tile 0 (qt0 = p)
  if (w <= p) KVDMA(w);

  for (int ti = 0; ti < 2; ++ti) {
    const int qt = ti ? (127 - p) : p;
    const int qb = qt * 32;

    bf16x8 qf[4];
    #pragma unroll
    for (int kc = 0; kc < 4; ++kc)
      qf[kc] = *reinterpret_cast<const bf16x8*>(Qb + (qb + q) * ADIM + kc * 16 + h * 8);

    f32x16 o0 = {0,0,0,0,0,0,0,0,0,0,0,0,0,0,0,0};
    f32x16 o1 = {0,0,0,0,0,0,0,0,0,0,0,0,0,0,0,0};
    float l = 0.f;

    for (int st = w; st <= qt; st += 12) {
      const int kv0 = st * 32;

      // this visit's K+V DMA (only outstanding vm ops) must be complete
      asm volatile("s_waitcnt vmcnt(0)" ::: "memory");
      __builtin_amdgcn_sched_barrier(0);

      bf16x8 kf0 = *kfp0, kf1 = *kfp1, kf2 = *kfp2, kf3 = *kfp3;
      bf16x8 vf00 = *vfp00, vf01 = *vfp01, vf10 = *vfp10, vf11 = *vfp11;
      // slot free once reads land; then issue next visit's DMA
      asm volatile("s_waitcnt lgkmcnt(0)" ::: "memory");
      __builtin_amdgcn_sched_barrier(0);
      if (st + 12 <= qt) KVDMA(st + 12);
      __builtin_amdgcn_sched_barrier(0);

      // S^T = K Q^T : lane(q,h) reg(i*4+j) = S[key=kv0+j+8i+4h][qb+q]
      f32x16 s = {0,0,0,0,0,0,0,0,0,0,0,0,0,0,0,0};
      __builtin_amdgcn_s_setprio(1);
      s = mfma32(kf0, qf[0], s);
      s = mfma32(kf1, qf[1], s);
      s = mfma32(kf2, qf[2], s);
      s = mfma32(kf3, qf[3], s);
      __builtin_amdgcn_s_setprio(0);

      // causal mask — only the diagonal tile
      if (st == qt) {
        #pragma unroll
        for (int i = 0; i < 4; ++i)
          #pragma unroll
          for (int j = 0; j < 4; ++j)
            if (kv0 + j + 8 * i + 4 * h > qb + q) s[i * 4 + j] = -INFINITY;
      }

      // max-free softmax: p = exp2(s) via raw v_exp_f32; 4-way sum tree
      float rs0 = 0.f, rs1 = 0.f, rs2 = 0.f, rs3 = 0.f;
      #pragma unroll
      for (int rr = 0; rr < 4; ++rr) {
        float e0 = exp2raw(s[4 * rr + 0]);
        float e1 = exp2raw(s[4 * rr + 1]);
        float e2 = exp2raw(s[4 * rr + 2]);
        float e3 = exp2raw(s[4 * rr + 3]);
        s[4 * rr + 0] = e0; s[4 * rr + 1] = e1;
        s[4 * rr + 2] = e2; s[4 * rr + 3] = e3;
        rs0 += e0; rs1 += e1; rs2 += e2; rs3 += e3;
      }
      l += (rs0 + rs1) + (rs2 + rs3);

      // P^T fragments in-register via permlane32_swap (half 0: keys 0..15)
      {
        unsigned a0 = cvtpk(s[0], s[1]), a1 = cvtpk(s[2], s[3]);
        unsigned b0 = cvtpk(s[4], s[5]), b1 = cvtpk(s[6], s[7]);
        u32x2 r0 = pl32swap(a0, b0);
        u32x2 r1 = pl32swap(a1, b1);
        union { unsigned u[4]; bf16x8 v; } pa0;
        pa0.u[0] = r0.x; pa0.u[1] = r1.x;
        pa0.u[2] = r0.y; pa0.u[3] = r1.y;
        __builtin_amdgcn_s_setprio(1);
        o0 = mfma32(vf00, pa0.v, o0);
        o1 = mfma32(vf10, pa0.v, o1);
        __builtin_amdgcn_s_setprio(0);
      }
      // half 1: keys 16..31
      {
        unsigned c0 = cvtpk(s[8],  s[9]),  c1 = cvtpk(s[10], s[11]);
        unsigned d0 = cvtpk(s[12], s[13]), d1 = cvtpk(s[14], s[15]);
        u32x2 r0 = pl32swap(c0, d0);
        u32x2 r1 = pl32swap(c1, d1);
        union { unsigned u[4]; bf16x8 v; } pa1;
        pa1.u[0] = r0.x; pa1.u[1] = r1.x;
        pa1.u[2] = r0.y; pa1.u[3] = r1.y;
        __builtin_amdgcn_s_setprio(1);
        o0 = mfma32(vf01, pa1.v, o0);
        o1 = mfma32(vf11, pa1.v, o1);
        __builtin_amdgcn_s_setprio(0);
      }
    }

    // issue tile-1's prologue DMA now (same addresses as tile-0 prologue).
    if (ti == 0) KVDMA(w);
    __builtin_amdgcn_sched_barrier(0);

    // publish partials as bf16 (C/D layout: d = dc*32 + 8*r2 + 4*h + j)
    #pragma unroll
    for (int r2 = 0; r2 < 4; ++r2) {
      uint2 u0, u1;
      u0.x = cvtpk(o0[r2*4+0], o0[r2*4+1]); u0.y = cvtpk(o0[r2*4+2], o0[r2*4+3]);
      u1.x = cvtpk(o1[r2*4+0], o1[r2*4+1]); u1.y = cvtpk(o1[r2*4+2], o1[r2*4+3]);
      *reinterpret_cast<uint2*>(&OldsU[w][q][8 * r2 + 4 * h])      = u0;
      *reinterpret_cast<uint2*>(&OldsU[w][q][32 + 8 * r2 + 4 * h]) = u1;
    }
    const float lt = l + __shfl_xor(l, 32);
    if (h == 0) Llds[w][q] = lt;
    // raw barrier: drain LDS writes only, leave prefetch vmcnt in flight
    asm volatile("s_waitcnt lgkmcnt(0)" ::: "memory");
    __builtin_amdgcn_sched_barrier(0);
    __builtin_amdgcn_s_barrier();
    __builtin_amdgcn_sched_barrier(0);

    // combine 12 partials: plain sum. threads 0..511 -> (q=t>>4, 4 dims)
    if (t < 512) {
      const int cq = t >> 4;
      const int cd = (t & 15) * 4;
      float lf = 0.f;
      float o4[4] = {0.f, 0.f, 0.f, 0.f};
      #pragma unroll
      for (int w2 = 0; w2 < 12; ++w2) {
        lf += Llds[w2][cq];
        const uint2 uv = *reinterpret_cast<const uint2*>(&OldsU[w2][cq][cd]);
        o4[0] += __uint_as_float(uv.x << 16);
        o4[1] += __uint_as_float(uv.x & 0xffff0000u);
        o4[2] += __uint_as_float(uv.y << 16);
        o4[3] += __uint_as_float(uv.y & 0xffff0000u);
      }
      const float inv = 1.f / lf;
      float4 res;
      res.x = o4[0] * inv; res.y = o4[1] * inv;
      res.z = o4[2] * inv; res.w = o4[3] * inv;
      *reinterpret_cast<float4*>(out + ((long long)b * SEQ + qb + cq) * ADIM + cd) = res;
    }
    // raw barrier: protect OldsU reuse by next tile (no vmcnt drain)
    asm volatile("s_waitcnt lgkmcnt(0)" ::: "memory");
    __builtin_amdgcn_sched_barrier(0);
    __builtin_amdgcn_s_barrier();
    __builtin_amdgcn_sched_barrier(0);
  }
  #undef KVDMA
}

extern "C" void kernel_launch(void* const* d_in, const int* in_sizes, int n_in,
                              void* d_out, int out_size, void* d_ws, size_t ws_size,
                              hipStream_t stream) {
  const float* x  = (const float*)d_in[0];
  const float* Wq = (const float*)d_in[1];
  const float* Wk = (const float*)d_in[2];
  const float* Wv = (const float*)d_in[3];

  const size_t qkvElems = (size_t)NBATCH * SEQ * ADIM;
  bf16* Qs = (bf16*)d_ws;
  bf16* Ks = Qs + qkvElems;
  bf16* Vt = Ks + qkvElems;

  proj_kernel<<<NBATCH * SEQ / 64, 256, 0, stream>>>(x, Wq, Wk, Wv, Qs, Ks, Vt);
  attn_kernel<<<256, 768, 0, stream>>>(Qs, Ks, Vt, (float*)d_out);
}

// Round 22
// 42.796 us; speedup vs baseline: 1.0632x; 1.0632x over previous
//
#include <hip/hip_runtime.h>
#include <hip/hip_bf16.h>
#include <math.h>

#define EMBED  768
#define SEQ    4096
#define ADIM   64
#define NBATCH 4
#define QSCALE (0.125f * 1.44269504088896340736f)

typedef __bf16 bf16;
typedef unsigned int u32;
typedef __attribute__((ext_vector_type(2))) unsigned u32x2;
typedef __attribute__((ext_vector_type(8))) __bf16 bf16x8;
typedef __attribute__((ext_vector_type(4))) __bf16 bf16x4;
typedef __attribute__((ext_vector_type(4))) float f32x4;
typedef __attribute__((ext_vector_type(16))) float f32x16;

__device__ __forceinline__ f32x4 mfma16(bf16x8 a, bf16x8 b, f32x4 c) {
  return __builtin_amdgcn_mfma_f32_16x16x32_bf16(a, b, c, 0, 0, 0);
}
__device__ __forceinline__ f32x16 mfma32(bf16x8 a, bf16x8 b, f32x16 c) {
  return __builtin_amdgcn_mfma_f32_32x32x16_bf16(a, b, c, 0, 0, 0);
}
__device__ __forceinline__ unsigned cvtpk(float lo, float hi) {
  unsigned d;
  asm("v_cvt_pk_bf16_f32 %0, %1, %2" : "=v"(d) : "v"(lo), "v"(hi));
  return d;
}
// raw native exp2 (v_exp_f32): avoids OCML denormal-fixup bloat.
__device__ __forceinline__ float exp2raw(float x) {
  float r;
  asm("v_exp_f32 %0, %1" : "=v"(r) : "v"(x));
  return r;
}
// half-wave swap: ret.x = {a_lo | b_lo}, ret.y = {a_hi | b_hi}
__device__ __forceinline__ u32x2 pl32swap(unsigned a, unsigned b) {
  return __builtin_amdgcn_permlane32_swap(a, b, false, false);
}
// async 16B-per-lane global -> LDS DMA (lane i lands at ldsbase + i*16B)
__device__ __forceinline__ void gl_lds16(const bf16* g, bf16* l) {
  __builtin_amdgcn_global_load_lds(
      (const __attribute__((address_space(1))) u32*)g,
      (__attribute__((address_space(3))) u32*)l, 16, 0, 0);
}

// ---------------------------------------------------------------------------
// Projection GEMM (R15/R20 VERBATIM — best measured config). M=32 rows/block,
// 512 blocks x 256 thr (2 blocks/CU). W staged DIRECTLY from fp32 (inline
// cvt, QSCALE folded into Wq). Double-buffered LDS stride-40 (2-way banks
// only), T14 async-stage split. V written KV-TILE-BLOCKED
// Vt[b][s/32][d][s%32] (4KB/tile).
// NOTE: M-scaling attempts failed 4x (R7/R8/R16 VGPR cliff at 512 thr;
// R21 M=64@256thr lost block-level latency hiding). This shape is final.
// ---------------------------------------------------------------------------
__global__ __launch_bounds__(256, 4) void proj_kernel(
    const float* __restrict__ x,
    const float* __restrict__ Wq, const float* __restrict__ Wk,
    const float* __restrict__ Wv,
    bf16* __restrict__ Qs, bf16* __restrict__ Ks, bf16* __restrict__ Vt)
{
  __shared__ bf16 Wl[2][192][40];
  __shared__ bf16 Xl[2][32][40];

  const int t    = threadIdx.x;
  const int lane = t & 63;
  const int w    = t >> 6;
  const int band = w >> 1;
  const int half = w & 1;
  const int r    = lane & 15;
  const int g    = lane >> 4;
  const long long row0 = (long long)blockIdx.x * 32;

  f32x4 acc[6];
  #pragma unroll
  for (int i = 0; i < 6; ++i) acc[i] = f32x4{0.f, 0.f, 0.f, 0.f};

  const int wrow = t >> 2;              // 0..63
  const int wg   = t & 3;
  const long long woff = (long long)wrow * EMBED + wg * 8;
  const float* wqs = Wq + woff;
  const float* wks = Wk + woff;
  const float* wvs = Wv + woff;
  const int xrow = t >> 3;              // 0..31
  const int xcol = (t & 7) * 4;
  const float* xsrc = x + (row0 + xrow) * EMBED + xcol;

  #define WWRITE(buf, base, va, vb, sc)                                      \
    {                                                                        \
      uint2 p0, p1;                                                          \
      p0.x = cvtpk(va.x * sc, va.y * sc);                                    \
      p0.y = cvtpk(va.z * sc, va.w * sc);                                    \
      p1.x = cvtpk(vb.x * sc, vb.y * sc);                                    \
      p1.y = cvtpk(vb.z * sc, vb.w * sc);                                    \
      *reinterpret_cast<uint2*>(&Wl[buf][(base) + wrow][wg * 8])     = p0;   \
      *reinterpret_cast<uint2*>(&Wl[buf][(base) + wrow][wg * 8 + 4]) = p1;   \
    }

  {
    float4 qa = *reinterpret_cast<const float4*>(wqs);
    float4 qb = *reinterpret_cast<const float4*>(wqs + 4);
    float4 ka = *reinterpret_cast<const float4*>(wks);
    float4 kb = *reinterpret_cast<const float4*>(wks + 4);
    float4 va = *reinterpret_cast<const float4*>(wvs);
    float4 vb = *reinterpret_cast<const float4*>(wvs + 4);
    float4 xv = *reinterpret_cast<const float4*>(xsrc);
    WWRITE(0, 0,   qa, qb, QSCALE);
    WWRITE(0, 64,  ka, kb, 1.0f);
    WWRITE(0, 128, va, vb, 1.0f);
    uint2 xp; xp.x = cvtpk(xv.x, xv.y); xp.y = cvtpk(xv.z, xv.w);
    *reinterpret_cast<uint2*>(&Xl[0][xrow][xcol]) = xp;
  }
  float4 xv_n = *reinterpret_cast<const float4*>(xsrc + 32);   // for kt=1
  __syncthreads();

  int cur = 0;
  for (int kt = 0; kt < 24; ++kt) {
    float4 qa, qb, ka, kb, va, vb, xv_n2;
    const bool pfW = kt < 23;
    if (pfW) {
      const int k0n = (kt + 1) * 32;
      qa = *reinterpret_cast<const float4*>(wqs + k0n);
      qb = *reinterpret_cast<const float4*>(wqs + k0n + 4);
      ka = *reinterpret_cast<const float4*>(wks + k0n);
      kb = *reinterpret_cast<const float4*>(wks + k0n + 4);
      va = *reinterpret_cast<const float4*>(wvs + k0n);
      vb = *reinterpret_cast<const float4*>(wvs + k0n + 4);
    }
    if (kt < 22)
      xv_n2 = *reinterpret_cast<const float4*>(xsrc + (kt + 2) * 32);

    bf16x8 af = *reinterpret_cast<const bf16x8*>(&Xl[cur][band * 16 + r][g * 8]);
    #pragma unroll
    for (int i = 0; i < 6; ++i) {
      const int n = half * 6 + i;
      bf16x8 bfrag = *reinterpret_cast<const bf16x8*>(&Wl[cur][n * 16 + r][g * 8]);
      acc[i] = mfma16(af, bfrag, acc[i]);
    }

    if (pfW) {
      WWRITE(cur ^ 1, 0,   qa, qb, QSCALE);
      WWRITE(cur ^ 1, 64,  ka, kb, 1.0f);
      WWRITE(cur ^ 1, 128, va, vb, 1.0f);
      uint2 xp; xp.x = cvtpk(xv_n.x, xv_n.y); xp.y = cvtpk(xv_n.z, xv_n.w);
      *reinterpret_cast<uint2*>(&Xl[cur ^ 1][xrow][xcol]) = xp;
    }
    xv_n = xv_n2;
    __syncthreads();
    cur ^= 1;
  }
  #undef WWRITE

  const long long rowbase = row0 + band * 16 + g * 4;
  const int bb = (int)(rowbase >> 12);
  const int ss = (int)(rowbase & 4095);
  #pragma unroll
  for (int i = 0; i < 6; ++i) {
    const int gt = half * 6 + i;
    if (gt < 4) {
      #pragma unroll
      for (int j = 0; j < 4; ++j)
        Qs[(rowbase + j) * ADIM + gt * 16 + r] = (bf16)(acc[i][j]);
    } else if (gt < 8) {
      #pragma unroll
      for (int j = 0; j < 4; ++j)
        Ks[(rowbase + j) * ADIM + (gt - 4) * 16 + r] = (bf16)(acc[i][j]);
    } else {
      const int d = (gt - 8) * 16 + r;
      bf16x4 pack;
      pack[0] = (bf16)(acc[i][0]); pack[1] = (bf16)(acc[i][1]);
      pack[2] = (bf16)(acc[i][2]); pack[3] = (bf16)(acc[i][3]);
      *reinterpret_cast<bf16x4*>(
          &Vt[(((long long)bb * 128 + (ss >> 5)) * 64 + d) * 32 + (ss & 31)]) = pack;
    }
  }
}

// ---------------------------------------------------------------------------
// Flash attention — R20 VERBATIM (42.8us config): K+V exact-line LDS-DMA,
// prefetch-distance-1, max-free softmax with raw v_exp_f32, permlane32_swap
// P^T build, tile-1 prologue prefetch + raw s_barrier combine.
// ---------------------------------------------------------------------------
__global__ __launch_bounds__(768) void attn_kernel(
    const bf16* __restrict__ Qs, const bf16* __restrict__ Ks,
    const bf16* __restrict__ Vt, float* __restrict__ out)
{
  __shared__ bf16 Kst[12][2048];                // 48 KB
  __shared__ bf16 Vst[12][2048];                // 48 KB
  __shared__ unsigned short OldsU[12][32][72];  // 55.3 KB
  __shared__ float Llds[12][32];                // 1.5 KB

  const int t    = threadIdx.x;
  const int lane = t & 63;
  const int w    = t >> 6;        // 0..11
  const int q    = lane & 31;
  const int h    = lane >> 5;
  const int bi   = blockIdx.x;    // 256 blocks
  const int b    = bi & 3;
  const int p    = bi >> 2;       // 0..63

  const bf16* Qb = Qs + (long long)b * SEQ * ADIM;
  const bf16* Kb = Ks + (long long)b * SEQ * ADIM;
  const bf16* Vb = Vt + (long long)b * SEQ * ADIM;  // [128][64][32] tiled

  const int Ri = lane >> 3;
  const int ci = lane & 7;
  const bf16* kdma = Kb + (long long)Ri * ADIM + (ci ^ Ri) * 8;
  bf16* kslot = &Kst[w][0];
  const int vd = lane >> 2;
  const int vc = lane & 3;
  const bf16* vdma = Vb + (long long)vd * 32 + ((vc ^ (vd & 3)) * 8);
  bf16* vslot = &Vst[w][0];

  const char* kbase = (const char*)kslot;
  const bf16x8* kfp0 = (const bf16x8*)(kbase + q * 128 + (((0 + h) ^ (q & 7)) << 4));
  const bf16x8* kfp1 = (const bf16x8*)(kbase + q * 128 + (((2 + h) ^ (q & 7)) << 4));
  const bf16x8* kfp2 = (const bf16x8*)(kbase + q * 128 + (((4 + h) ^ (q & 7)) << 4));
  const bf16x8* kfp3 = (const bf16x8*)(kbase + q * 128 + (((6 + h) ^ (q & 7)) << 4));
  const char* vbase = (const char*)vslot;
  const bf16x8* vfp00 = (const bf16x8*)(vbase + q * 64        + (((0 + h) ^ (q & 3)) << 4));
  const bf16x8* vfp01 = (const bf16x8*)(vbase + q * 64        + (((2 + h) ^ (q & 3)) << 4));
  const bf16x8* vfp10 = (const bf16x8*)(vbase + 2048 + q * 64 + (((0 + h) ^ (q & 3)) << 4));
  const bf16x8* vfp11 = (const bf16x8*)(vbase + 2048 + q * 64 + (((2 + h) ^ (q & 3)) << 4));

  #define KVDMA(st_)                                                         \
    {                                                                        \
      const bf16* ksrc = kdma + (long long)((st_) * 32) * ADIM;              \
      gl_lds16(ksrc,             kslot);                                     \
      gl_lds16(ksrc +  8 * ADIM, kslot + 512);                               \
      gl_lds16(ksrc + 16 * ADIM, kslot + 1024);                              \
      gl_lds16(ksrc + 24 * ADIM, kslot + 1536);                              \
      const bf16* vsrc = vdma + (long long)(st_) * 2048;                     \
      gl_lds16(vsrc,        vslot);                                          \
      gl_lds16(vsrc +  512, vslot + 512);                                    \
      gl_lds16(vsrc + 1024, vslot + 1024);                                   \
      gl_lds16(vsrc + 1536, vslot + 1536);                                   \
    }

  // prologue DMA for tile 0 (qt0 = p)
  if (w <= p) KVDMA(w);

  for (int ti = 0; ti < 2; ++ti) {
    const int qt = ti ? (127 - p) : p;
    const int qb = qt * 32;

    bf16x8 qf[4];
    #pragma unroll
    for (int kc = 0; kc < 4; ++kc)
      qf[kc] = *reinterpret_cast<const bf16x8*>(Qb + (qb + q) * ADIM + kc * 16 + h * 8);

    f32x16 o0 = {0,0,0,0,0,0,0,0,0,0,0,0,0,0,0,0};
    f32x16 o1 = {0,0,0,0,0,0,0,0,0,0,0,0,0,0,0,0};
    float l = 0.f;

    for (int st = w; st <= qt; st += 12) {
      const int kv0 = st * 32;

      // this visit's K+V DMA (only outstanding vm ops) must be complete
      asm volatile("s_waitcnt vmcnt(0)" ::: "memory");
      __builtin_amdgcn_sched_barrier(0);

      bf16x8 kf0 = *kfp0, kf1 = *kfp1, kf2 = *kfp2, kf3 = *kfp3;
      bf16x8 vf00 = *vfp00, vf01 = *vfp01, vf10 = *vfp10, vf11 = *vfp11;
      // slot free once reads land; then issue next visit's DMA
      asm volatile("s_waitcnt lgkmcnt(0)" ::: "memory");
      __builtin_amdgcn_sched_barrier(0);
      if (st + 12 <= qt) KVDMA(st + 12);
      __builtin_amdgcn_sched_barrier(0);

      // S^T = K Q^T : lane(q,h) reg(i*4+j) = S[key=kv0+j+8i+4h][qb+q]
      f32x16 s = {0,0,0,0,0,0,0,0,0,0,0,0,0,0,0,0};
      __builtin_amdgcn_s_setprio(1);
      s = mfma32(kf0, qf[0], s);
      s = mfma32(kf1, qf[1], s);
      s = mfma32(kf2, qf[2], s);
      s = mfma32(kf3, qf[3], s);
      __builtin_amdgcn_s_setprio(0);

      // causal mask — only the diagonal tile
      if (st == qt) {
        #pragma unroll
        for (int i = 0; i < 4; ++i)
          #pragma unroll
          for (int j = 0; j < 4; ++j)
            if (kv0 + j + 8 * i + 4 * h > qb + q) s[i * 4 + j] = -INFINITY;
      }

      // max-free softmax: p = exp2(s) via raw v_exp_f32; 4-way sum tree
      float rs0 = 0.f, rs1 = 0.f, rs2 = 0.f, rs3 = 0.f;
      #pragma unroll
      for (int rr = 0; rr < 4; ++rr) {
        float e0 = exp2raw(s[4 * rr + 0]);
        float e1 = exp2raw(s[4 * rr + 1]);
        float e2 = exp2raw(s[4 * rr + 2]);
        float e3 = exp2raw(s[4 * rr + 3]);
        s[4 * rr + 0] = e0; s[4 * rr + 1] = e1;
        s[4 * rr + 2] = e2; s[4 * rr + 3] = e3;
        rs0 += e0; rs1 += e1; rs2 += e2; rs3 += e3;
      }
      l += (rs0 + rs1) + (rs2 + rs3);

      // P^T fragments in-register via permlane32_swap (half 0: keys 0..15)
      {
        unsigned a0 = cvtpk(s[0], s[1]), a1 = cvtpk(s[2], s[3]);
        unsigned b0 = cvtpk(s[4], s[5]), b1 = cvtpk(s[6], s[7]);
        u32x2 r0 = pl32swap(a0, b0);
        u32x2 r1 = pl32swap(a1, b1);
        union { unsigned u[4]; bf16x8 v; } pa0;
        pa0.u[0] = r0.x; pa0.u[1] = r1.x;
        pa0.u[2] = r0.y; pa0.u[3] = r1.y;
        __builtin_amdgcn_s_setprio(1);
        o0 = mfma32(vf00, pa0.v, o0);
        o1 = mfma32(vf10, pa0.v, o1);
        __builtin_amdgcn_s_setprio(0);
      }
      // half 1: keys 16..31
      {
        unsigned c0 = cvtpk(s[8],  s[9]),  c1 = cvtpk(s[10], s[11]);
        unsigned d0 = cvtpk(s[12], s[13]), d1 = cvtpk(s[14], s[15]);
        u32x2 r0 = pl32swap(c0, d0);
        u32x2 r1 = pl32swap(c1, d1);
        union { unsigned u[4]; bf16x8 v; } pa1;
        pa1.u[0] = r0.x; pa1.u[1] = r1.x;
        pa1.u[2] = r0.y; pa1.u[3] = r1.y;
        __builtin_amdgcn_s_setprio(1);
        o0 = mfma32(vf01, pa1.v, o0);
        o1 = mfma32(vf11, pa1.v, o1);
        __builtin_amdgcn_s_setprio(0);
      }
    }

    // issue tile-1's prologue DMA now (same addresses as tile-0 prologue).
    if (ti == 0) KVDMA(w);
    __builtin_amdgcn_sched_barrier(0);

    // publish partials as bf16 (C/D layout: d = dc*32 + 8*r2 + 4*h + j)
    #pragma unroll
    for (int r2 = 0; r2 < 4; ++r2) {
      uint2 u0, u1;
      u0.x = cvtpk(o0[r2*4+0], o0[r2*4+1]); u0.y = cvtpk(o0[r2*4+2], o0[r2*4+3]);
      u1.x = cvtpk(o1[r2*4+0], o1[r2*4+1]); u1.y = cvtpk(o1[r2*4+2], o1[r2*4+3]);
      *reinterpret_cast<uint2*>(&OldsU[w][q][8 * r2 + 4 * h])      = u0;
      *reinterpret_cast<uint2*>(&OldsU[w][q][32 + 8 * r2 + 4 * h]) = u1;
    }
    const float lt = l + __shfl_xor(l, 32);
    if (h == 0) Llds[w][q] = lt;
    // raw barrier: drain LDS writes only, leave prefetch vmcnt in flight
    asm volatile("s_waitcnt lgkmcnt(0)" ::: "memory");
    __builtin_amdgcn_sched_barrier(0);
    __builtin_amdgcn_s_barrier();
    __builtin_amdgcn_sched_barrier(0);

    // combine 12 partials: plain sum. threads 0..511 -> (q=t>>4, 4 dims)
    if (t < 512) {
      const int cq = t >> 4;
      const int cd = (t & 15) * 4;
      float lf = 0.f;
      float o4[4] = {0.f, 0.f, 0.f, 0.f};
      #pragma unroll
      for (int w2 = 0; w2 < 12; ++w2) {
        lf += Llds[w2][cq];
        const uint2 uv = *reinterpret_cast<const uint2*>(&OldsU[w2][cq][cd]);
        o4[0] += __uint_as_float(uv.x << 16);
        o4[1] += __uint_as_float(uv.x & 0xffff0000u);
        o4[2] += __uint_as_float(uv.y << 16);
        o4[3] += __uint_as_float(uv.y & 0xffff0000u);
      }
      const float inv = 1.f / lf;
      float4 res;
      res.x = o4[0] * inv; res.y = o4[1] * inv;
      res.z = o4[2] * inv; res.w = o4[3] * inv;
      *reinterpret_cast<float4*>(out + ((long long)b * SEQ + qb + cq) * ADIM + cd) = res;
    }
    // raw barrier: protect OldsU reuse by next tile (no vmcnt drain)
    asm volatile("s_waitcnt lgkmcnt(0)" ::: "memory");
    __builtin_amdgcn_sched_barrier(0);
    __builtin_amdgcn_s_barrier();
    __builtin_amdgcn_sched_barrier(0);
  }
  #undef KVDMA
}

extern "C" void kernel_launch(void* const* d_in, const int* in_sizes, int n_in,
                              void* d_out, int out_size, void* d_ws, size_t ws_size,
                              hipStream_t stream) {
  const float* x  = (const float*)d_in[0];
  const float* Wq = (const float*)d_in[1];
  const float* Wk = (const float*)d_in[2];
  const float* Wv = (const float*)d_in[3];

  const size_t qkvElems = (size_t)NBATCH * SEQ * ADIM;
  bf16* Qs = (bf16*)d_ws;
  bf16* Ks = Qs + qkvElems;
  bf16* Vt = Ks + qkvElems;

  proj_kernel<<<NBATCH * SEQ / 32, 256, 0, stream>>>(x, Wq, Wk, Wv, Qs, Ks, Vt);
  attn_kernel<<<256, 768, 0, stream>>>(Qs, Ks, Vt, (float*)d_out);
}